// Round 1
// baseline (763.499 us; speedup 1.0000x reference)
//
#include <hip/hip_runtime.h>
#include <hip/hip_bf16.h>

// Problem constants (from reference)
#define B_    8
#define C_    128
#define H_    64
#define W_    64
#define COUT_ 128
#define K_    3
#define K2_   9
#define JOFF_ 18            // 2*K*K offset channels
#define HW_   (H_*W_)       // 4096
#define CK_   (C_*K2_)      // 1152
#define P_    8             // spatial positions per block in deform kernel

// ---------------------------------------------------------------------------
// Kernel A: offset conv (3x3, pad 1, stride 1) + bias
// One thread per (b, j, ho, wo); wo fastest -> coalesced x reads.
// ---------------------------------------------------------------------------
__global__ __launch_bounds__(256) void offset_conv_kernel(
    const float* __restrict__ x, const float* __restrict__ w_off,
    const float* __restrict__ b_off, float* __restrict__ offs)
{
    int tid = blockIdx.x * blockDim.x + threadIdx.x;
    int wo = tid & 63;
    int ho = (tid >> 6) & 63;
    int j  = (tid >> 12) % JOFF_;
    int b  = tid / (HW_ * JOFF_);
    if (b >= B_) return;

    // Precompute tap masks + clamped flat indices (boundary-safe, branchless)
    float m[K2_];
    int   idx[K2_];
#pragma unroll
    for (int ky = 0; ky < 3; ++ky) {
#pragma unroll
        for (int kx = 0; kx < 3; ++kx) {
            int y  = ho - 1 + ky;
            int xx = wo - 1 + kx;
            bool v = (y >= 0) & (y < H_) & (xx >= 0) & (xx < W_);
            int yc  = min(max(y, 0), H_ - 1);
            int xc  = min(max(xx, 0), W_ - 1);
            m[ky*3+kx]   = v ? 1.0f : 0.0f;
            idx[ky*3+kx] = yc * W_ + xc;
        }
    }

    float acc = b_off[j];
    const float* xb = x + (size_t)b * (C_*HW_);
    const float* wj = w_off + (size_t)j * (C_*K2_);
    for (int c = 0; c < C_; ++c) {
        const float* xc = xb + c * HW_;
        const float* wc = wj + c * K2_;
#pragma unroll
        for (int k = 0; k < K2_; ++k) {
            acc = fmaf(xc[idx[k]] * m[k], wc[k], acc);
        }
    }
    offs[tid] = acc;
}

// ---------------------------------------------------------------------------
// Kernel B: deformable conv. One block (128 threads) handles P_=8 consecutive
// spatial positions (same batch b since 4096 % P_ == 0).
// Phase 0: bilinear corner indices + masked weights -> LDS
// Phase 1: val[p][c*9+k] -> LDS (thread = channel c)
// Phase 2: out[o] = sum_i w_def[o][i] * val[p][i]  (thread = out channel o)
// ---------------------------------------------------------------------------
__global__ __launch_bounds__(128) void deform_kernel(
    const float* __restrict__ x, const float* __restrict__ offs,
    const float* __restrict__ w_def, float* __restrict__ out)
{
    __shared__ float val[P_][CK_];            // 36864 B
    __shared__ int   s_y0[P_][K2_], s_y1[P_][K2_];
    __shared__ int   s_x0[P_][K2_], s_x1[P_][K2_];
    __shared__ float s_w00[P_][K2_], s_w01[P_][K2_];
    __shared__ float s_w10[P_][K2_], s_w11[P_][K2_];

    const int t     = threadIdx.x;
    const int sbase = blockIdx.x * P_;        // linear spatial base (b*4096 + hw)
    const int b     = sbase >> 12;

    // ---- Phase 0: bilinear setup for 8 positions x 9 taps = 72 entries
    if (t < P_ * K2_) {
        int p = t / K2_, k = t % K2_;
        int s  = sbase + p;
        int hw = s & (HW_ - 1);
        int ho = hw >> 6, wo = hw & 63;
        float dy = offs[(((size_t)b * JOFF_ + 2*k    ) << 12) + hw];
        float dx = offs[(((size_t)b * JOFF_ + 2*k + 1) << 12) + hw];
        float py = (float)(ho - 1 + (k / 3)) + dy;
        float px = (float)(wo - 1 + (k % 3)) + dx;
        float y0f = floorf(py), x0f = floorf(px);
        float wy = py - y0f,    wx = px - x0f;
        int y0 = (int)y0f, x0 = (int)x0f;
        int y1 = y0 + 1,   x1 = x0 + 1;
        float vy0 = (y0 >= 0 && y0 < H_) ? 1.f : 0.f;
        float vy1 = (y1 >= 0 && y1 < H_) ? 1.f : 0.f;
        float vx0 = (x0 >= 0 && x0 < W_) ? 1.f : 0.f;
        float vx1 = (x1 >= 0 && x1 < W_) ? 1.f : 0.f;
        s_w00[p][k] = (1.f - wy) * (1.f - wx) * vy0 * vx0;
        s_w01[p][k] = (1.f - wy) * wx         * vy0 * vx1;
        s_w10[p][k] = wy         * (1.f - wx) * vy1 * vx0;
        s_w11[p][k] = wy         * wx         * vy1 * vx1;
        s_y0[p][k] = min(max(y0, 0), H_ - 1);
        s_y1[p][k] = min(max(y1, 0), H_ - 1);
        s_x0[p][k] = min(max(x0, 0), W_ - 1);
        s_x1[p][k] = min(max(x1, 0), W_ - 1);
    }
    __syncthreads();

    // ---- Phase 1: gather + bilinear, thread = channel
    {
        const int c = t;
        const float* xc = x + ((size_t)(b * C_ + c)) * HW_;
        for (int p = 0; p < P_; ++p) {
#pragma unroll
            for (int k = 0; k < K2_; ++k) {
                int y0 = s_y0[p][k], y1 = s_y1[p][k];
                int x0 = s_x0[p][k], x1 = s_x1[p][k];
                float v = s_w00[p][k] * xc[y0 * W_ + x0]
                        + s_w01[p][k] * xc[y0 * W_ + x1]
                        + s_w10[p][k] * xc[y1 * W_ + x0]
                        + s_w11[p][k] * xc[y1 * W_ + x1];
                val[p][c * K2_ + k] = v;
            }
        }
    }
    __syncthreads();

    // ---- Phase 2: matvec per position, thread = output channel
    {
        const int o = t;
        float acc[P_];
#pragma unroll
        for (int p = 0; p < P_; ++p) acc[p] = 0.f;
        const float* wrow = w_def + (size_t)o * CK_;
        for (int i = 0; i < CK_; i += 4) {
            float4 w4 = *reinterpret_cast<const float4*>(wrow + i);
#pragma unroll
            for (int p = 0; p < P_; ++p) {
                const float4 v4 = *reinterpret_cast<const float4*>(&val[p][i]);
                float a = acc[p];
                a = fmaf(w4.x, v4.x, a);
                a = fmaf(w4.y, v4.y, a);
                a = fmaf(w4.z, v4.z, a);
                a = fmaf(w4.w, v4.w, a);
                acc[p] = a;
            }
        }
        const int hwb = sbase & (HW_ - 1);
#pragma unroll
        for (int p = 0; p < P_; ++p) {
            out[(((size_t)(b * COUT_ + o)) << 12) + hwb + p] = acc[p];
        }
    }
}

// ---------------------------------------------------------------------------
extern "C" void kernel_launch(void* const* d_in, const int* in_sizes, int n_in,
                              void* d_out, int out_size, void* d_ws, size_t ws_size,
                              hipStream_t stream) {
    const float* x     = (const float*)d_in[0];
    const float* w_off = (const float*)d_in[1];
    const float* b_off = (const float*)d_in[2];
    const float* w_def = (const float*)d_in[3];
    float* out  = (float*)d_out;
    float* offs = (float*)d_ws;   // B*18*64*64 f32 = 2,359,296 B

    // Kernel A: offsets
    {
        int total  = B_ * JOFF_ * HW_;          // 589,824
        int blocks = (total + 255) / 256;       // 2304
        offset_conv_kernel<<<blocks, 256, 0, stream>>>(x, w_off, b_off, offs);
    }
    // Kernel B: deformable conv
    {
        int blocks = (B_ * HW_) / P_;           // 4096
        deform_kernel<<<blocks, 128, 0, stream>>>(x, offs, w_def, out);
    }
}

// Round 2
// 444.358 us; speedup vs baseline: 1.7182x; 1.7182x over previous
//
#include <hip/hip_runtime.h>
#include <hip/hip_bf16.h>

// Problem constants (from reference)
#define B_    8
#define C_    128
#define H_    64
#define W_    64
#define COUT_ 128
#define K_    3
#define K2_   9
#define JOFF_ 18            // 2*K*K offset channels
#define HW_   (H_*W_)       // 4096
#define CK_   (C_*K2_)      // 1152

typedef short  short8 __attribute__((ext_vector_type(8)));   // 8 bf16 in 4 VGPR
typedef float  f32x4  __attribute__((ext_vector_type(4)));

__device__ __forceinline__ ushort f2bf(float f) {
    __hip_bfloat16 h = __float2bfloat16(f);
    return *reinterpret_cast<ushort*>(&h);
}

// ---------------------------------------------------------------------------
// Kernel A: offset conv (3x3, pad 1, stride 1) + bias  (unchanged, ~90us)
// ---------------------------------------------------------------------------
__global__ __launch_bounds__(256) void offset_conv_kernel(
    const float* __restrict__ x, const float* __restrict__ w_off,
    const float* __restrict__ b_off, float* __restrict__ offs)
{
    int tid = blockIdx.x * blockDim.x + threadIdx.x;
    int wo = tid & 63;
    int ho = (tid >> 6) & 63;
    int j  = (tid >> 12) % JOFF_;
    int b  = tid / (HW_ * JOFF_);
    if (b >= B_) return;

    float m[K2_];
    int   idx[K2_];
#pragma unroll
    for (int ky = 0; ky < 3; ++ky) {
#pragma unroll
        for (int kx = 0; kx < 3; ++kx) {
            int y  = ho - 1 + ky;
            int xx = wo - 1 + kx;
            bool v = (y >= 0) & (y < H_) & (xx >= 0) & (xx < W_);
            int yc  = min(max(y, 0), H_ - 1);
            int xc  = min(max(xx, 0), W_ - 1);
            m[ky*3+kx]   = v ? 1.0f : 0.0f;
            idx[ky*3+kx] = yc * W_ + xc;
        }
    }

    float acc = b_off[j];
    const float* xb = x + (size_t)b * (C_*HW_);
    const float* wj = w_off + (size_t)j * (C_*K2_);
    for (int c = 0; c < C_; ++c) {
        const float* xc = xb + c * HW_;
        const float* wc = wj + c * K2_;
#pragma unroll
        for (int k = 0; k < K2_; ++k) {
            acc = fmaf(xc[idx[k]] * m[k], wc[k], acc);
        }
    }
    offs[tid] = acc;
}

// ---------------------------------------------------------------------------
// Kernel T: transpose/convert w_def -> wt[k][o][c ^ ((o&7)<<3)] bf16.
// The XOR pre-swizzle makes the GEMM's A-tile a LINEAR copy into LDS while
// keeping ds_read_b128 fragment reads bank-conflict-free.
// ---------------------------------------------------------------------------
__global__ __launch_bounds__(256) void transpose_wdef_kernel(
    const float* __restrict__ w_def, ushort* __restrict__ wt)
{
    int t = blockIdx.x * 256 + threadIdx.x;
    if (t >= K2_ * COUT_ * C_) return;
    int c = t & 127;
    int o = (t >> 7) & 127;
    int k = t >> 14;
    float v = w_def[((size_t)o * C_ + c) * K2_ + k];
    wt[((size_t)k * COUT_ + o) * C_ + (c ^ ((o & 7) << 3))] = f2bf(v);
}

// ---------------------------------------------------------------------------
// Kernel B: fused deformable gather + MFMA GEMM.
// Block = 256 threads (4 waves, 2x2 wave grid). Output tile: all 128 out
// channels x 64 consecutive positions (one image row). K-loop: 9 taps x
// 4 chunks of 32 channels, mfma_f32_16x16x32_bf16.
// ---------------------------------------------------------------------------
__global__ __launch_bounds__(256) void deform_mfma_kernel(
    const float* __restrict__ x, const float* __restrict__ offs,
    const ushort* __restrict__ wt, float* __restrict__ out)
{
    __shared__ float  s_w[K2_][4][64];     // bilinear weights [tap][corner][s]
    __shared__ int    s_i[K2_][4][64];     // clamped flat idx
    __shared__ ushort sA[COUT_][C_];       // w_def tap tile (pre-swizzled) 32KB
    __shared__ ushort sB[64][C_];          // valT[s][c] (swizzled)        16KB

    const int t   = threadIdx.x;
    const int s0  = blockIdx.x * 64;       // linear spatial base b*4096 + hw0
    const int b   = s0 >> 12;
    const int hw0 = s0 & (HW_ - 1);        // row-aligned (64 | 4096)
    const int ho  = hw0 >> 6;

    // ---- Phase 0: bilinear tables (9 taps x 64 positions)
    for (int e = t; e < K2_ * 64; e += 256) {
        int k = e >> 6, s = e & 63;
        float dy = offs[((size_t)(b*JOFF_ + 2*k    ) << 12) + hw0 + s];
        float dx = offs[((size_t)(b*JOFF_ + 2*k + 1) << 12) + hw0 + s];
        float py = (float)(ho - 1 + k/3) + dy;
        float px = (float)(s  - 1 + k%3) + dx;
        float y0f = floorf(py), x0f = floorf(px);
        float wy = py - y0f,    wx = px - x0f;
        int y0 = (int)y0f, x0 = (int)x0f;
        int y1 = y0 + 1,   x1 = x0 + 1;
        float vy0 = (y0 >= 0 && y0 < H_) ? 1.f : 0.f;
        float vy1 = (y1 >= 0 && y1 < H_) ? 1.f : 0.f;
        float vx0 = (x0 >= 0 && x0 < W_) ? 1.f : 0.f;
        float vx1 = (x1 >= 0 && x1 < W_) ? 1.f : 0.f;
        int y0c = min(max(y0, 0), H_-1), y1c = min(max(y1, 0), H_-1);
        int x0c = min(max(x0, 0), W_-1), x1c = min(max(x1, 0), W_-1);
        s_w[k][0][s] = (1.f-wy)*(1.f-wx)*vy0*vx0;  s_i[k][0][s] = y0c*W_ + x0c;
        s_w[k][1][s] = (1.f-wy)*wx      *vy0*vx1;  s_i[k][1][s] = y0c*W_ + x1c;
        s_w[k][2][s] = wy      *(1.f-wx)*vy1*vx0;  s_i[k][2][s] = y1c*W_ + x0c;
        s_w[k][3][s] = wy      *wx      *vy1*vx1;  s_i[k][3][s] = y1c*W_ + x1c;
    }
    __syncthreads();

    const int wid = t >> 6, lane = t & 63;
    const int wm = wid >> 1, wn = wid & 1;   // 2x2 wave grid: 64(M) x 32(N) per wave
    const int sg = t & 63;                   // gather lane = position
    const int cq = t >> 6;                   // gather channel-quarter 0..3
    const float* xb = x + ((size_t)b << 19); // b * C * HW

    f32x4 acc[4][2] = {};

    for (int k = 0; k < K2_; ++k) {
        // ---- stage A tap tile: linear 32KB copy (pre-swizzled in wt)
        {
            const float4* src = reinterpret_cast<const float4*>(wt + (size_t)k * (COUT_*C_));
            float4* dst = reinterpret_cast<float4*>(&sA[0][0]);
#pragma unroll
            for (int i = 0; i < 8; ++i) dst[t + i*256] = src[t + i*256];
        }
        // ---- gather B tile: valT[s][c] bf16, swizzled writes
        {
            int   ixr[4]; float wr[4];
#pragma unroll
            for (int r = 0; r < 4; ++r) { ixr[r] = s_i[k][r][sg]; wr[r] = s_w[k][r][sg]; }
            const int swz = (sg & 7) << 3;
#pragma unroll
            for (int i = 0; i < 16; ++i) {
                int c0 = (cq + i*4) * 2;                 // even channels 0..126
                const float* xc0 = xb + ((size_t)c0 << 12);
                const float* xc1 = xc0 + HW_;
                float v0 = 0.f, v1 = 0.f;
#pragma unroll
                for (int r = 0; r < 4; ++r) {
                    v0 = fmaf(wr[r], xc0[ixr[r]], v0);
                    v1 = fmaf(wr[r], xc1[ixr[r]], v1);
                }
                uint pk = (uint)f2bf(v0) | ((uint)f2bf(v1) << 16);
                *reinterpret_cast<uint*>(&sB[sg][c0 ^ swz]) = pk;
            }
        }
        __syncthreads();

        // ---- MFMA: 4 chunks of K=32 channels
#pragma unroll
        for (int kc = 0; kc < 4; ++kc) {
            const int kk = kc*32 + ((lane >> 4) << 3);   // 8 contiguous c per lane
            short8 aF[4], bF[2];
#pragma unroll
            for (int mi = 0; mi < 4; ++mi) {
                int o = wm*64 + mi*16 + (lane & 15);
                aF[mi] = *reinterpret_cast<const short8*>(&sA[o][kk ^ ((o & 7) << 3)]);
            }
#pragma unroll
            for (int ni = 0; ni < 2; ++ni) {
                int s = wn*32 + ni*16 + (lane & 15);
                bF[ni] = *reinterpret_cast<const short8*>(&sB[s][kk ^ ((s & 7) << 3)]);
            }
#pragma unroll
            for (int mi = 0; mi < 4; ++mi)
#pragma unroll
                for (int ni = 0; ni < 2; ++ni)
                    acc[mi][ni] = __builtin_amdgcn_mfma_f32_16x16x32_bf16(
                        aF[mi], bF[ni], acc[mi][ni], 0, 0, 0);
        }
        __syncthreads();
    }

    // ---- epilogue: C/D layout col=lane&15, row=(lane>>4)*4+reg
#pragma unroll
    for (int mi = 0; mi < 4; ++mi) {
#pragma unroll
        for (int ni = 0; ni < 2; ++ni) {
#pragma unroll
            for (int r = 0; r < 4; ++r) {
                int o = wm*64 + mi*16 + ((lane >> 4) * 4 + r);
                int s = wn*32 + ni*16 + (lane & 15);
                out[(((size_t)(b*COUT_ + o)) << 12) + hw0 + s] = acc[mi][ni][r];
            }
        }
    }
}

// ---------------------------------------------------------------------------
extern "C" void kernel_launch(void* const* d_in, const int* in_sizes, int n_in,
                              void* d_out, int out_size, void* d_ws, size_t ws_size,
                              hipStream_t stream) {
    const float* x     = (const float*)d_in[0];
    const float* w_off = (const float*)d_in[1];
    const float* b_off = (const float*)d_in[2];
    const float* w_def = (const float*)d_in[3];
    float* out  = (float*)d_out;

    float*  offs = (float*)d_ws;                                    // 2,359,296 B
    ushort* wt   = (ushort*)((char*)d_ws + (size_t)B_*JOFF_*HW_*4); //   294,912 B

    // Kernel A: offsets
    {
        int total  = B_ * JOFF_ * HW_;
        int blocks = (total + 255) / 256;
        offset_conv_kernel<<<blocks, 256, 0, stream>>>(x, w_off, b_off, offs);
    }
    // Kernel T: w_def -> bf16, tap-major, pre-swizzled
    {
        int total  = K2_ * COUT_ * C_;
        int blocks = (total + 255) / 256;
        transpose_wdef_kernel<<<blocks, 256, 0, stream>>>(w_def, wt);
    }
    // Kernel B: fused gather + MFMA GEMM
    {
        int blocks = (B_ * HW_) / 64;   // 512
        deform_mfma_kernel<<<blocks, 256, 0, stream>>>(x, offs, wt, out);
    }
}

// Round 3
// 280.282 us; speedup vs baseline: 2.7240x; 1.5854x over previous
//
#include <hip/hip_runtime.h>
#include <hip/hip_bf16.h>

// Problem constants (from reference)
#define B_    8
#define C_    128
#define H_    64
#define W_    64
#define COUT_ 128
#define K_    3
#define K2_   9
#define JOFF_ 18            // 2*K*K offset channels
#define HW_   (H_*W_)       // 4096
#define CK_   (C_*K2_)      // 1152

typedef short  short8 __attribute__((ext_vector_type(8)));   // 8 bf16 in 4 VGPR
typedef float  f32x4  __attribute__((ext_vector_type(4)));

__device__ __forceinline__ ushort f2bf(float f) {
    __hip_bfloat16 h = __float2bfloat16(f);
    return *reinterpret_cast<ushort*>(&h);
}

// ---------------------------------------------------------------------------
// Kernel A: offset conv (3x3, pad 1, stride 1) + bias.
// Block = one (b,row): 4 waves = 4 channel-quarters, each thread keeps all
// 18 output-channel accumulators in VGPRs (x loaded once, reused 18x).
// Wave-uniform weight base via readfirstlane -> scalar loads.
// ---------------------------------------------------------------------------
__global__ __launch_bounds__(256) void offset_conv_kernel(
    const float* __restrict__ x, const float* __restrict__ w_off,
    const float* __restrict__ b_off, float* __restrict__ offs)
{
    __shared__ float red[3][JOFF_][64];      // 13.8 KB partials from waves 1..3

    const int bid  = blockIdx.x;             // 512 blocks
    const int nbid = ((bid & 7) << 6) + (bid >> 3);   // XCD chunking: 1 image/XCD
    const int b    = nbid >> 6;
    const int row  = nbid & 63;

    const int t  = threadIdx.x;
    const int s  = t & 63;                   // position in row
    const int wv = t >> 6;                   // channel quarter 0..3
    const int wvu = __builtin_amdgcn_readfirstlane(wv);

    // 9-tap masks + clamped flat indices at (row, s)
    float m[K2_]; int idx[K2_];
#pragma unroll
    for (int ky = 0; ky < 3; ++ky) {
#pragma unroll
        for (int kx = 0; kx < 3; ++kx) {
            int y  = row - 1 + ky;
            int xx = s  - 1 + kx;
            bool v = (y >= 0) & (y < H_) & (xx >= 0) & (xx < W_);
            int yc = min(max(y, 0), H_ - 1);
            int xc = min(max(xx, 0), W_ - 1);
            m[ky*3+kx]   = v ? 1.0f : 0.0f;
            idx[ky*3+kx] = yc * W_ + xc;
        }
    }

    const float* xb = x + ((size_t)b << 19) + ((size_t)wvu << 17);  // b,c-quarter
    const float* wb = w_off + wvu * 32 * K2_;                       // uniform base

    float acc[JOFF_];
#pragma unroll
    for (int j = 0; j < JOFF_; ++j) acc[j] = 0.f;

    for (int c = 0; c < 32; ++c) {
        const float* xc = xb + (c << 12);
        float xv[K2_];
#pragma unroll
        for (int k = 0; k < K2_; ++k) xv[k] = xc[idx[k]] * m[k];
#pragma unroll
        for (int k = 0; k < K2_; ++k) {
            const float* wp = wb + c * K2_ + k;
#pragma unroll
            for (int j = 0; j < JOFF_; ++j)
                acc[j] = fmaf(wp[(size_t)j * CK_], xv[k], acc[j]);
        }
    }

    if (wv > 0) {
#pragma unroll
        for (int j = 0; j < JOFF_; ++j) red[wv-1][j][s] = acc[j];
    }
    __syncthreads();
    if (wv == 0) {
#pragma unroll
        for (int j = 0; j < JOFF_; ++j) {
            float r = acc[j] + red[0][j][s] + red[1][j][s] + red[2][j][s] + b_off[j];
            offs[((size_t)(b * JOFF_ + j) << 12) + (row << 6) + s] = r;
        }
    }
}

// ---------------------------------------------------------------------------
// Kernel T: w_def -> wt[k][o][c] bf16 (tap-major, linear; A is read straight
// from L2 by the GEMM, no LDS staging, so no pre-swizzle needed).
// ---------------------------------------------------------------------------
__global__ __launch_bounds__(256) void transpose_wdef_kernel(
    const float* __restrict__ w_def, ushort* __restrict__ wt)
{
    int t = blockIdx.x * 256 + threadIdx.x;
    if (t >= K2_ * COUT_ * C_) return;
    int c = t & 127;
    int o = (t >> 7) & 127;
    int k = t >> 14;
    float v = w_def[((size_t)o * C_ + c) * K2_ + k];
    wt[((size_t)k * COUT_ + o) * C_ + c] = f2bf(v);
}

// ---------------------------------------------------------------------------
// Kernel B: fused deformable gather + MFMA GEMM.
// Block = 256 threads (4 waves, 2x2 wave grid), 128 out channels x 64
// positions (one image row). Per tap: A fragments direct from global (L2),
// gather -> swizzled sB, one barrier pair, 32 MFMA.
// ---------------------------------------------------------------------------
__global__ __launch_bounds__(256, 3) void deform_mfma_kernel(
    const float* __restrict__ x, const float* __restrict__ offs,
    const ushort* __restrict__ wt, float* __restrict__ out)
{
    __shared__ ushort sB[64][C_];            // 16 KB, XOR-swizzled
    __shared__ float  s_off[JOFF_][64];      // 4.6 KB raw offsets for this row

    const int bid  = blockIdx.x;             // 512 blocks
    const int nbid = ((bid & 7) << 6) + (bid >> 3);   // XCD chunking: 1 image/XCD
    const int s0   = nbid << 6;
    const int b    = s0 >> 12;
    const int hw0  = s0 & (HW_ - 1);
    const int ho   = hw0 >> 6;

    const int t    = threadIdx.x;
    const int wid  = t >> 6, lane = t & 63;
    const int wm   = wid >> 1, wn = wid & 1; // 2x2 wave grid: 64(M) x 32(N)
    const int sg   = lane;                   // gather position = lane
    const int cq   = wid;                    // gather channel quarter
    const float* xb = x + ((size_t)b << 19);

    // Phase 0: cache this row's 18 offset planes in LDS (coalesced)
    for (int e = t; e < JOFF_ * 64; e += 256) {
        int j = e >> 6, s = e & 63;
        s_off[j][s] = offs[((size_t)(b * JOFF_ + j) << 12) + hw0 + s];
    }
    __syncthreads();

    f32x4 acc[4][2] = {};
    const int swz  = (sg & 7) << 3;
    const int arow = lane & 15;
    const int akk  = (lane >> 4) << 3;

    for (int k = 0; k < K2_; ++k) {
        // ---- A fragments: 16 x b128 direct from global (L2-resident wt).
        // Issued first; latency hides under the gather phase.
        short8 aF[4][4];
        const ushort* wk = wt + (size_t)k * (COUT_ * C_);
#pragma unroll
        for (int kc = 0; kc < 4; ++kc)
#pragma unroll
            for (int mi = 0; mi < 4; ++mi)
                aF[kc][mi] = *reinterpret_cast<const short8*>(
                    wk + (wm*64 + mi*16 + arow) * C_ + kc*32 + akk);

        // ---- bilinear setup for this lane's position (registers only)
        float dy = s_off[2*k    ][sg];
        float dx = s_off[2*k + 1][sg];
        float py = (float)(ho - 1 + k/3) + dy;
        float px = (float)(sg - 1 + k%3) + dx;
        float y0f = floorf(py), x0f = floorf(px);
        float wy = py - y0f,    wx = px - x0f;
        int y0 = (int)y0f, x0 = (int)x0f;
        int y1 = y0 + 1,   x1 = x0 + 1;
        float vy0 = (y0 >= 0 && y0 < H_) ? 1.f : 0.f;
        float vy1 = (y1 >= 0 && y1 < H_) ? 1.f : 0.f;
        float vx0 = (x0 >= 0 && x0 < W_) ? 1.f : 0.f;
        float vx1 = (x1 >= 0 && x1 < W_) ? 1.f : 0.f;
        int y0c = min(max(y0, 0), H_-1), y1c = min(max(y1, 0), H_-1);
        int x0c = min(max(x0, 0), W_-1), x1c = min(max(x1, 0), W_-1);
        float wr[4]; int ixr[4];
        wr[0] = (1.f-wy)*(1.f-wx)*vy0*vx0;  ixr[0] = y0c*W_ + x0c;
        wr[1] = (1.f-wy)*wx      *vy0*vx1;  ixr[1] = y0c*W_ + x1c;
        wr[2] = wy      *(1.f-wx)*vy1*vx0;  ixr[2] = y1c*W_ + x0c;
        wr[3] = wy      *wx      *vy1*vx1;  ixr[3] = y1c*W_ + x1c;

        // ---- gather B tile: valT[s][c] bf16, swizzled writes
#pragma unroll
        for (int i = 0; i < 16; ++i) {
            int c0 = (cq + i*4) * 2;                 // even channels 0..126
            const float* xc0 = xb + ((size_t)c0 << 12);
            const float* xc1 = xc0 + HW_;
            float v0 = 0.f, v1 = 0.f;
#pragma unroll
            for (int r = 0; r < 4; ++r) {
                v0 = fmaf(wr[r], xc0[ixr[r]], v0);
                v1 = fmaf(wr[r], xc1[ixr[r]], v1);
            }
            uint pk = (uint)f2bf(v0) | ((uint)f2bf(v1) << 16);
            *reinterpret_cast<uint*>(&sB[sg][c0 ^ swz]) = pk;
        }
        __syncthreads();

        // ---- MFMA: 4 chunks of K=32 channels
#pragma unroll
        for (int kc = 0; kc < 4; ++kc) {
            short8 bF[2];
#pragma unroll
            for (int ni = 0; ni < 2; ++ni) {
                int srow = wn*32 + ni*16 + (lane & 15);
                bF[ni] = *reinterpret_cast<const short8*>(
                    &sB[srow][(kc*32 + akk) ^ ((srow & 7) << 3)]);
            }
#pragma unroll
            for (int mi = 0; mi < 4; ++mi)
#pragma unroll
                for (int ni = 0; ni < 2; ++ni)
                    acc[mi][ni] = __builtin_amdgcn_mfma_f32_16x16x32_bf16(
                        aF[kc][mi], bF[ni], acc[mi][ni], 0, 0, 0);
        }
        __syncthreads();
    }

    // ---- epilogue: C/D layout col=lane&15, row=(lane>>4)*4+reg
#pragma unroll
    for (int mi = 0; mi < 4; ++mi) {
#pragma unroll
        for (int ni = 0; ni < 2; ++ni) {
#pragma unroll
            for (int r = 0; r < 4; ++r) {
                int o = wm*64 + mi*16 + ((lane >> 4) * 4 + r);
                int s = wn*32 + ni*16 + (lane & 15);
                out[(((size_t)(b*COUT_ + o)) << 12) + hw0 + s] = acc[mi][ni][r];
            }
        }
    }
}

// ---------------------------------------------------------------------------
extern "C" void kernel_launch(void* const* d_in, const int* in_sizes, int n_in,
                              void* d_out, int out_size, void* d_ws, size_t ws_size,
                              hipStream_t stream) {
    const float* x     = (const float*)d_in[0];
    const float* w_off = (const float*)d_in[1];
    const float* b_off = (const float*)d_in[2];
    const float* w_def = (const float*)d_in[3];
    float* out  = (float*)d_out;

    float*  offs = (float*)d_ws;                                    // 2,359,296 B
    ushort* wt   = (ushort*)((char*)d_ws + (size_t)B_*JOFF_*HW_*4); //   294,912 B

    // Kernel A: offsets (one block per (b,row))
    {
        offset_conv_kernel<<<B_ * H_, 256, 0, stream>>>(x, w_off, b_off, offs);
    }
    // Kernel T: w_def -> bf16 tap-major
    {
        int total  = K2_ * COUT_ * C_;
        int blocks = (total + 255) / 256;
        transpose_wdef_kernel<<<blocks, 256, 0, stream>>>(w_def, wt);
    }
    // Kernel B: fused gather + MFMA GEMM
    {
        int blocks = (B_ * HW_) / 64;   // 512
        deform_mfma_kernel<<<blocks, 256, 0, stream>>>(x, offs, wt, out);
    }
}